// Round 12
// baseline (585.262 us; speedup 1.0000x reference)
//
#include <hip/hip_runtime.h>
#include <hip/hip_bf16.h>
#include <stdint.h>

// Problem constants
#define N_TOK 8192
#define IN_DIM 1024
#define CDIM 512
#define NW 1536  // 3*CDIM stacked Wk,Wv,Wq

typedef short bf16x8 __attribute__((ext_vector_type(8)));
typedef float f32x4 __attribute__((ext_vector_type(4)));

__device__ __forceinline__ unsigned short f2bf(float f) {
  union { float f; unsigned int u; } x; x.f = f;
  unsigned int u = x.u;
  u += 0x7fffu + ((u >> 16) & 1u);   // round-to-nearest-even
  return (unsigned short)(u >> 16);
}
__device__ __forceinline__ float bf2f(unsigned short us) {
  union { unsigned int u; float f; } x; x.u = ((unsigned int)us) << 16;
  return x.f;
}

#define GLD16(g, l) __builtin_amdgcn_global_load_lds( \
    (const __attribute__((address_space(1))) void*)(g), \
    (__attribute__((address_space(3))) void*)(l), 16, 0, 0)

// ---------------------------------------------------------------------------
// K0: convert fp32 inputs -> bf16 staging buffers.
// ---------------------------------------------------------------------------
__global__ __launch_bounds__(256) void k_convert(
    const float* __restrict__ u, const float* __restrict__ z,
    const float* __restrict__ wk, const float* __restrict__ wv,
    const float* __restrict__ wq,
    ushort* __restrict__ Sb, ushort* __restrict__ Wb) {
  const int S4 = N_TOK * IN_DIM / 4;   // 2097152
  const int W4 = NW * IN_DIM / 4;      // 393216
  const int total = S4 + W4;
  for (int e = blockIdx.x * blockDim.x + threadIdx.x; e < total;
       e += gridDim.x * blockDim.x) {
    float4 v; ushort* dst;
    if (e < S4) {
      int idx = e << 2; int row = idx >> 10; int col = idx & 1023;
      const float* src = (col < 512) ? (u + row * 512 + col)
                                     : (z + row * 512 + (col - 512));
      v = *(const float4*)src;
      dst = Sb + idx;
    } else {
      int idx = (e - S4) << 2; int row = idx >> 10; int col = idx & 1023;
      const float* base = (row < 512) ? wk : (row < 1024 ? wv : wq);
      v = *(const float4*)(base + (size_t)(row & 511) * 1024 + col);
      dst = Wb + idx;
    }
    ushort4 o;
    o.x = f2bf(v.x); o.y = f2bf(v.y); o.z = f2bf(v.z); o.w = f2bf(v.w);
    *(ushort4*)dst = o;
  }
}

// ---------------------------------------------------------------------------
// K1: fused K/V/Q projection (bt-GEMM, 128x128 tile, BK=64).
// ---------------------------------------------------------------------------
__global__ __launch_bounds__(256) void k_kvq(
    const ushort* __restrict__ Sb, const ushort* __restrict__ Wb,
    const float* __restrict__ bk, const float* __restrict__ bv,
    const float* __restrict__ bq,
    ushort* __restrict__ Kb, ushort* __restrict__ Qb, ushort* __restrict__ VT) {
  __shared__ __align__(16) ushort As[128 * 64];
  __shared__ __align__(16) ushort Bs[128 * 64];
  const int tid = threadIdx.x, lane = tid & 63, w = tid >> 6;
  const int wr = w >> 1, wc = w & 1;
  const int tm = blockIdx.x, tn = blockIdx.y;

  f32x4 acc[4][4];
#pragma unroll
  for (int m = 0; m < 4; m++)
#pragma unroll
    for (int n = 0; n < 4; n++) acc[m][n] = (f32x4){0.f, 0.f, 0.f, 0.f};

  const ushort* ga0 = Sb + (size_t)tm * 128 * IN_DIM;
  const ushort* gb0 = Wb + (size_t)tn * 128 * IN_DIM;

  for (int k0 = 0; k0 < IN_DIM; k0 += 64) {
#pragma unroll
    for (int i = 0; i < 4; i++) {
      int ce = i * 256 + tid;
      int row = ce >> 3, c8 = (ce & 7) << 3;
      GLD16(ga0 + (size_t)row * IN_DIM + k0 + c8, As + ce * 8);
      GLD16(gb0 + (size_t)row * IN_DIM + k0 + c8, Bs + ce * 8);
    }
    __syncthreads();
#pragma unroll
    for (int kb = 0; kb < 2; kb++) {
      bf16x8 af[4], bfr[4];
#pragma unroll
      for (int m = 0; m < 4; m++)
        af[m] = *(const bf16x8*)(As + (wr * 64 + m * 16 + (lane & 15)) * 64 +
                                 kb * 32 + ((lane >> 4) << 3));
#pragma unroll
      for (int n = 0; n < 4; n++)
        bfr[n] = *(const bf16x8*)(Bs + (wc * 64 + n * 16 + (lane & 15)) * 64 +
                                  kb * 32 + ((lane >> 4) << 3));
#pragma unroll
      for (int m = 0; m < 4; m++)
#pragma unroll
        for (int n = 0; n < 4; n++)
          acc[m][n] = __builtin_amdgcn_mfma_f32_16x16x32_bf16(af[m], bfr[n],
                                                              acc[m][n], 0, 0, 0);
    }
    __syncthreads();
  }

  const int region = tn >> 2;                 // 0=K 1=V 2=Q
  const int colr = (tn & 3) * 128 + wc * 64;
  const int rbase = tm * 128 + wr * 64;
  const float* bias = (region == 0) ? bk : (region == 1 ? bv : bq);
  if (region == 1) {
#pragma unroll
    for (int m = 0; m < 4; m++) {
      int r0 = rbase + m * 16 + ((lane >> 4) << 2);
#pragma unroll
      for (int n = 0; n < 4; n++) {
        int c = colr + n * 16 + (lane & 15);
        float b = bias[c];
        ushort4 pk;
        pk.x = f2bf(acc[m][n][0] + b);
        pk.y = f2bf(acc[m][n][1] + b);
        pk.z = f2bf(acc[m][n][2] + b);
        pk.w = f2bf(acc[m][n][3] + b);
        *(ushort4*)(VT + (size_t)c * N_TOK + r0) = pk;  // transposed store
      }
    }
  } else {
    ushort* O = (region == 0) ? Kb : Qb;
#pragma unroll
    for (int m = 0; m < 4; m++) {
      int r0 = rbase + m * 16 + ((lane >> 4) << 2);
#pragma unroll
      for (int n = 0; n < 4; n++) {
        int c = colr + n * 16 + (lane & 15);
        float b = bias[c];
#pragma unroll
        for (int rg = 0; rg < 4; rg++)
          O[(size_t)(r0 + rg) * CDIM + c] = f2bf(acc[m][n][rg] + b);
      }
    }
  }
}

// ---------------------------------------------------------------------------
// K2: scores = Q @ K^T / sqrt(512); E = bf16(exp(score)) (diag->0) + row sums.
// Round-8 epilogue (direct 2B stores — proven; LDS-repack regressed r10).
// ---------------------------------------------------------------------------
__global__ __launch_bounds__(256) void k_scores(
    const ushort* __restrict__ Qb, const ushort* __restrict__ Kb,
    ushort* __restrict__ E, float* __restrict__ rowpart) {
  __shared__ __align__(16) ushort As[128 * 64];
  __shared__ __align__(16) ushort Bs[128 * 64];
  __shared__ float sums[256];
  const int tid = threadIdx.x, lane = tid & 63, w = tid >> 6;
  const int wr = w >> 1, wc = w & 1;
  const int bid = blockIdx.x;
  const int swz = (bid & 7) * 512 + (bid >> 3);  // XCD-contiguous remap
  const int tm = swz & 63, tn = swz >> 6;

  f32x4 acc[4][4];
#pragma unroll
  for (int m = 0; m < 4; m++)
#pragma unroll
    for (int n = 0; n < 4; n++) acc[m][n] = (f32x4){0.f, 0.f, 0.f, 0.f};

  const ushort* ga0 = Qb + (size_t)tm * 128 * CDIM;
  const ushort* gb0 = Kb + (size_t)tn * 128 * CDIM;

  for (int k0 = 0; k0 < CDIM; k0 += 64) {
#pragma unroll
    for (int i = 0; i < 4; i++) {
      int ce = i * 256 + tid;
      int row = ce >> 3, c8 = (ce & 7) << 3;
      GLD16(ga0 + (size_t)row * CDIM + k0 + c8, As + ce * 8);
      GLD16(gb0 + (size_t)row * CDIM + k0 + c8, Bs + ce * 8);
    }
    __syncthreads();
#pragma unroll
    for (int kb = 0; kb < 2; kb++) {
      bf16x8 af[4], bfr[4];
#pragma unroll
      for (int m = 0; m < 4; m++)
        af[m] = *(const bf16x8*)(As + (wr * 64 + m * 16 + (lane & 15)) * 64 +
                                 kb * 32 + ((lane >> 4) << 3));
#pragma unroll
      for (int n = 0; n < 4; n++)
        bfr[n] = *(const bf16x8*)(Bs + (wc * 64 + n * 16 + (lane & 15)) * 64 +
                                  kb * 32 + ((lane >> 4) << 3));
#pragma unroll
      for (int m = 0; m < 4; m++)
#pragma unroll
        for (int n = 0; n < 4; n++)
          acc[m][n] = __builtin_amdgcn_mfma_f32_16x16x32_bf16(af[m], bfr[n],
                                                              acc[m][n], 0, 0, 0);
    }
    __syncthreads();
  }

  const float scale = 0.044194173824159216f;  // 1/sqrt(512)
  float rs[4][4];
#pragma unroll
  for (int m = 0; m < 4; m++)
#pragma unroll
    for (int rg = 0; rg < 4; rg++) rs[m][rg] = 0.f;

#pragma unroll
  for (int m = 0; m < 4; m++) {
    int grow_b = tm * 128 + wr * 64 + m * 16 + ((lane >> 4) << 2);
#pragma unroll
    for (int n = 0; n < 4; n++) {
      int gcol = tn * 128 + wc * 64 + n * 16 + (lane & 15);
#pragma unroll
      for (int rg = 0; rg < 4; rg++) {
        int grow = grow_b + rg;
        float ev = (grow == gcol) ? 0.0f : __expf(acc[m][n][rg] * scale);
        unsigned short evb = f2bf(ev);
        E[(size_t)grow * N_TOK + gcol] = evb;
        rs[m][rg] += bf2f(evb);
      }
    }
  }
#pragma unroll
  for (int m = 0; m < 4; m++)
#pragma unroll
    for (int rg = 0; rg < 4; rg++) {
      float s = rs[m][rg];
      s += __shfl_xor(s, 1);
      s += __shfl_xor(s, 2);
      s += __shfl_xor(s, 4);
      s += __shfl_xor(s, 8);
      rs[m][rg] = s;
    }
  if ((lane & 15) == 0) {
#pragma unroll
    for (int m = 0; m < 4; m++)
#pragma unroll
      for (int rg = 0; rg < 4; rg++)
        sums[wc * 128 + wr * 64 + m * 16 + ((lane >> 4) << 2) + rg] = rs[m][rg];
  }
  __syncthreads();
  if (tid < 128)
    rowpart[(size_t)(tm * 128 + tid) * 64 + tn] = sums[tid] + sums[128 + tid];
}

// ---------------------------------------------------------------------------
// K2c: rcp_l[row] = 1 / sum_j E[row][j]
// ---------------------------------------------------------------------------
__global__ __launch_bounds__(256) void k_rcp(const float* __restrict__ rowpart,
                                             float* __restrict__ rcp_l) {
  int row = blockIdx.x * blockDim.x + threadIdx.x;
  if (row < N_TOK) {
    const float4* p = (const float4*)(rowpart + (size_t)row * 64);
    float s = 0.f;
#pragma unroll
    for (int i = 0; i < 16; i++) {
      float4 v = p[i];
      s += v.x + v.y + v.z + v.w;
    }
    rcp_l[row] = 1.0f / s;
  }
}

// ---------------------------------------------------------------------------
// K3 (ws_mode): split-K(x4) PV with IN-LOOP fused attn write.
// 1024 blocks, m97 structure (BM=128,BN=128,BK=64, 4 waves, 32 MFMA/wave/
// step, swizzled global_load_lds, 2 barriers/step), 4 blocks/CU
// (__launch_bounds__(256,4) pins VGPR<=128).
// bid = (tm>>3)*128 + (kz*4+tn)*8 + (tm&7): the 4 tn-blocks sharing an
// E (tm,kz) panel are 8 apart -> same XCD -> one L2 fill (r11: FETCH clean).
// In-loop attn write: block (tm,tn,kz) owns attn cols [kz*2048+tn*512,+512)
// for its 128 rows — written during the 8 matching K-steps, reading E lines
// THIS BLOCK JUST STAGED (same K-step, guaranteed L2-hot). At 4 blocks/CU
// the store drain at the barrier's vmcnt(0) is covered (r3-5's neutral
// result was at 2 blocks/CU where it sat on the critical path).
// Partials kz -> p0..p3 (raw fp32), reduced by k_reduce4.
// ---------------------------------------------------------------------------
__global__ __launch_bounds__(256, 4) void k_pv_norm(
    const ushort* __restrict__ E, const ushort* __restrict__ VT,
    const float* __restrict__ rcp_l, float* __restrict__ part0,
    float* __restrict__ part1, float* __restrict__ part2,
    float* __restrict__ part3, float* __restrict__ attn) {
  __shared__ __align__(16) ushort As[128 * 64];
  __shared__ __align__(16) ushort Bs[128 * 64];
  const int bid = blockIdx.x;
  const int tid = threadIdx.x;
  const int lane = tid & 63, w = tid >> 6;
  const int wr = w >> 1, wc = w & 1;
  const int inner = (bid >> 3) & 15;           // kz*4 + tn
  const int tn = inner & 3, kz = inner >> 2;
  const int tm = ((bid >> 7) << 3) | (bid & 7);
  const int kbase = kz << 11;  // kz*2048, 32 K-steps of 64

  f32x4 acc[4][4];
#pragma unroll
  for (int m = 0; m < 4; m++)
#pragma unroll
    for (int n = 0; n < 4; n++) acc[m][n] = (f32x4){0.f, 0.f, 0.f, 0.f};

  const ushort* ga0 = E + (size_t)tm * 128 * N_TOK;
  const ushort* gb0 = VT + (size_t)tn * 128 * N_TOK;
  const int sx = lane & 7;  // read-side swizzle (frag row&7 == lane&7)
  const int kw_lo = kbase + (tn << 9);  // owned attn col range
  const int kw_hi = kw_lo + 512;

  for (int k0 = kbase; k0 < kbase + 2048; k0 += 64) {
#pragma unroll
    for (int i = 0; i < 4; i++) {
      int ce = i * 256 + tid;
      int row = ce >> 3;
      int c8 = ((ce & 7) ^ (row & 7)) << 3;  // pre-swizzled source chunk
      GLD16(ga0 + (size_t)row * N_TOK + k0 + c8, As + ce * 8);
      GLD16(gb0 + (size_t)row * N_TOK + k0 + c8, Bs + ce * 8);
    }
    __syncthreads();
#pragma unroll
    for (int kb = 0; kb < 2; kb++) {
      const int chunk = ((kb * 4 + (lane >> 4)) ^ sx) << 3;
      bf16x8 af[4], bfr[4];
#pragma unroll
      for (int m = 0; m < 4; m++)
        af[m] = *(const bf16x8*)(As + (wr * 64 + m * 16 + (lane & 15)) * 64 +
                                 chunk);
#pragma unroll
      for (int n = 0; n < 4; n++)
        bfr[n] = *(const bf16x8*)(Bs + (wc * 64 + n * 16 + (lane & 15)) * 64 +
                                  chunk);
#pragma unroll
      for (int m = 0; m < 4; m++)
#pragma unroll
        for (int n = 0; n < 4; n++)
          acc[m][n] = __builtin_amdgcn_mfma_f32_16x16x32_bf16(af[m], bfr[n],
                                                              acc[m][n], 0, 0, 0);
    }

    // in-loop fused attn write: 128 rows x 64 cols fp32; E read is L2-hot
    // (this block staged exactly these lines above).
    if (k0 >= kw_lo && k0 < kw_hi) {
#pragma unroll
      for (int p = 0; p < 4; p++) {
        int ce = p * 256 + tid;            // 0..1023
        int row = ce >> 3;                 // 0..127
        int c8 = (ce & 7) << 3;            // 0..56
        int grow = tm * 128 + row;
        float rl = rcp_l[grow];
        uint4 ev = *(const uint4*)(E + ((size_t)grow << 13) + k0 + c8);
        float4 o0, o1;
        o0.x = bf2f((unsigned short)(ev.x & 0xffffu)) * rl;
        o0.y = bf2f((unsigned short)(ev.x >> 16)) * rl;
        o0.z = bf2f((unsigned short)(ev.y & 0xffffu)) * rl;
        o0.w = bf2f((unsigned short)(ev.y >> 16)) * rl;
        o1.x = bf2f((unsigned short)(ev.z & 0xffffu)) * rl;
        o1.y = bf2f((unsigned short)(ev.z >> 16)) * rl;
        o1.z = bf2f((unsigned short)(ev.w & 0xffffu)) * rl;
        o1.w = bf2f((unsigned short)(ev.w >> 16)) * rl;
        float* op = attn + ((size_t)grow << 13) + k0 + c8;
        *(float4*)op = o0;
        *(float4*)(op + 4) = o1;
      }
    }
    __syncthreads();
  }

  float* P = (kz == 0) ? part0 : (kz == 1) ? part1 : (kz == 2) ? part2 : part3;
#pragma unroll
  for (int m = 0; m < 4; m++) {
    int r0 = tm * 128 + wr * 64 + m * 16 + ((lane >> 4) << 2);
#pragma unroll
    for (int n = 0; n < 4; n++) {
      int c = tn * 128 + wc * 64 + n * 16 + (lane & 15);
#pragma unroll
      for (int rg = 0; rg < 4; rg++)
        P[(size_t)(r0 + rg) * CDIM + c] = acc[m][n][rg];
    }
  }
}

// ---------------------------------------------------------------------------
// K3-fb (fallback only): pure split-K(x2) PV, same structure, 3D grid.
// ---------------------------------------------------------------------------
__global__ __launch_bounds__(256) void k_pv(
    const ushort* __restrict__ E, const ushort* __restrict__ VT,
    float* __restrict__ part0, float* __restrict__ part1) {
  __shared__ __align__(16) ushort As[128 * 64];
  __shared__ __align__(16) ushort Bs[128 * 64];
  const int tid = threadIdx.x, lane = tid & 63, w = tid >> 6;
  const int wr = w >> 1, wc = w & 1;
  const int tn = blockIdx.x, kz = blockIdx.y, tm = blockIdx.z;
  const int kbase = kz << 12;

  f32x4 acc[4][4];
#pragma unroll
  for (int m = 0; m < 4; m++)
#pragma unroll
    for (int n = 0; n < 4; n++) acc[m][n] = (f32x4){0.f, 0.f, 0.f, 0.f};

  const ushort* ga0 = E + (size_t)tm * 128 * N_TOK;
  const ushort* gb0 = VT + (size_t)tn * 128 * N_TOK;
  const int sx = lane & 7;

  for (int k0 = kbase; k0 < kbase + 4096; k0 += 64) {
#pragma unroll
    for (int i = 0; i < 4; i++) {
      int ce = i * 256 + tid;
      int row = ce >> 3;
      int c8 = ((ce & 7) ^ (row & 7)) << 3;
      GLD16(ga0 + (size_t)row * N_TOK + k0 + c8, As + ce * 8);
      GLD16(gb0 + (size_t)row * N_TOK + k0 + c8, Bs + ce * 8);
    }
    __syncthreads();
#pragma unroll
    for (int kb = 0; kb < 2; kb++) {
      const int chunk = ((kb * 4 + (lane >> 4)) ^ sx) << 3;
      bf16x8 af[4], bfr[4];
#pragma unroll
      for (int m = 0; m < 4; m++)
        af[m] = *(const bf16x8*)(As + (wr * 64 + m * 16 + (lane & 15)) * 64 +
                                 chunk);
#pragma unroll
      for (int n = 0; n < 4; n++)
        bfr[n] = *(const bf16x8*)(Bs + (wc * 64 + n * 16 + (lane & 15)) * 64 +
                                  chunk);
#pragma unroll
      for (int m = 0; m < 4; m++)
#pragma unroll
        for (int n = 0; n < 4; n++)
          acc[m][n] = __builtin_amdgcn_mfma_f32_16x16x32_bf16(af[m], bfr[n],
                                                              acc[m][n], 0, 0, 0);
    }
    __syncthreads();
  }

  float* P = kz ? part1 : part0;
#pragma unroll
  for (int m = 0; m < 4; m++) {
    int r0 = tm * 128 + wr * 64 + m * 16 + ((lane >> 4) << 2);
#pragma unroll
    for (int n = 0; n < 4; n++) {
      int c = tn * 128 + wc * 64 + n * 16 + (lane & 15);
#pragma unroll
      for (int rg = 0; rg < 4; rg++)
        P[(size_t)(r0 + rg) * CDIM + c] = acc[m][n][rg];
    }
  }
}

// ---------------------------------------------------------------------------
// K3b: mbar = (p0+p1+p2+p3) * rcp_l  (p0 lives in the mbar region; in-place).
// ---------------------------------------------------------------------------
__global__ __launch_bounds__(256) void k_reduce4(
    float* __restrict__ p0, const float* __restrict__ p1,
    const float* __restrict__ p2, const float* __restrict__ p3,
    const float* __restrict__ rcp_l) {
  int idx4 = blockIdx.x * blockDim.x + threadIdx.x;
  const int T4 = N_TOK * CDIM / 4;
  if (idx4 < T4) {
    int row = idx4 >> 7;
    float rl = rcp_l[row];
    float4 a = ((const float4*)p0)[idx4];
    float4 b = ((const float4*)p1)[idx4];
    float4 c = ((const float4*)p2)[idx4];
    float4 d = ((const float4*)p3)[idx4];
    float4 o;
    o.x = (a.x + b.x + c.x + d.x) * rl;
    o.y = (a.y + b.y + c.y + d.y) * rl;
    o.z = (a.z + b.z + c.z + d.z) * rl;
    o.w = (a.w + b.w + c.w + d.w) * rl;
    ((float4*)p0)[idx4] = o;
  }
}

// ---------------------------------------------------------------------------
// K3b2 (fallback): mbar = (p0+p1) * rcp_l
// ---------------------------------------------------------------------------
__global__ __launch_bounds__(256) void k_reduce2(
    float* __restrict__ p0, const float* __restrict__ p1,
    const float* __restrict__ rcp_l) {
  int idx4 = blockIdx.x * blockDim.x + threadIdx.x;
  const int T4 = N_TOK * CDIM / 4;
  if (idx4 < T4) {
    int row = idx4 >> 7;
    float rl = rcp_l[row];
    float4 a = ((const float4*)p0)[idx4];
    float4 b = ((const float4*)p1)[idx4];
    float4 o;
    o.x = (a.x + b.x) * rl; o.y = (a.y + b.y) * rl;
    o.z = (a.z + b.z) * rl; o.w = (a.w + b.w) * rl;
    ((float4*)p0)[idx4] = o;
  }
}

// ---------------------------------------------------------------------------
// K4 (fallback only): attn[row][j] = float(E[row][j]) * rcp_l[row]
// ---------------------------------------------------------------------------
__global__ __launch_bounds__(256) void k_norm(
    const ushort* __restrict__ E, float* __restrict__ attn,
    const float* __restrict__ rcp_l, int row0, int nrows) {
  const int units = nrows << 10;
  for (int uidx = blockIdx.x * blockDim.x + threadIdx.x; uidx < units;
       uidx += gridDim.x * blockDim.x) {
    int row = row0 + (uidx >> 10);
    int c8 = (uidx & 1023) << 3;
    const float rl = rcp_l[row];
    uint4 ev = *(const uint4*)(E + ((size_t)row << 13) + c8);
    float4 o0, o1;
    o0.x = bf2f((unsigned short)(ev.x & 0xffffu)) * rl;
    o0.y = bf2f((unsigned short)(ev.x >> 16)) * rl;
    o0.z = bf2f((unsigned short)(ev.y & 0xffffu)) * rl;
    o0.w = bf2f((unsigned short)(ev.y >> 16)) * rl;
    o1.x = bf2f((unsigned short)(ev.z & 0xffffu)) * rl;
    o1.y = bf2f((unsigned short)(ev.z >> 16)) * rl;
    o1.z = bf2f((unsigned short)(ev.w & 0xffffu)) * rl;
    o1.w = bf2f((unsigned short)(ev.w >> 16)) * rl;
    float* op = attn + ((size_t)row << 13) + c8;
    *(float4*)op = o0;
    *(float4*)(op + 4) = o1;
  }
}

// ---------------------------------------------------------------------------
// K4b (fallback only): last row — overlaps its own E source; regs first.
// ---------------------------------------------------------------------------
__global__ __launch_bounds__(256) void k_lastrow(
    const ushort* __restrict__ E, float* __restrict__ attn,
    const float* __restrict__ rcp_l) {
  const int row = N_TOK - 1;
  const int t = threadIdx.x;
  const float rl = rcp_l[row];
  const uint4* src = (const uint4*)(E + ((size_t)row << 13)) + t * 4;
  uint4 rr[4] = {src[0], src[1], src[2], src[3]};
  __syncthreads();
  float* dst = attn + ((size_t)row << 13) + t * 32;
#pragma unroll
  for (int q = 0; q < 4; q++) {
    float4 o0, o1;
    o0.x = bf2f((unsigned short)(rr[q].x & 0xffffu)) * rl;
    o0.y = bf2f((unsigned short)(rr[q].x >> 16)) * rl;
    o0.z = bf2f((unsigned short)(rr[q].y & 0xffffu)) * rl;
    o0.w = bf2f((unsigned short)(rr[q].y >> 16)) * rl;
    o1.x = bf2f((unsigned short)(rr[q].z & 0xffffu)) * rl;
    o1.y = bf2f((unsigned short)(rr[q].z >> 16)) * rl;
    o1.z = bf2f((unsigned short)(rr[q].w & 0xffffu)) * rl;
    o1.w = bf2f((unsigned short)(rr[q].w >> 16)) * rl;
    *(float4*)(dst + q * 8) = o0;
    *(float4*)(dst + q * 8 + 4) = o1;
  }
}

// ---------------------------------------------------------------------------
extern "C" void kernel_launch(void* const* d_in, const int* in_sizes, int n_in,
                              void* d_out, int out_size, void* d_ws,
                              size_t ws_size, hipStream_t stream) {
  const float* u  = (const float*)d_in[0];
  const float* z  = (const float*)d_in[1];
  const float* Wk = (const float*)d_in[2];
  const float* bk = (const float*)d_in[3];
  const float* Wv = (const float*)d_in[4];
  const float* bv = (const float*)d_in[5];
  const float* Wq = (const float*)d_in[6];
  const float* bq = (const float*)d_in[7];

  float* mbar = (float*)d_out;
  float* attn = (float*)d_out + (size_t)N_TOK * CDIM;

  char* ws = (char*)d_ws;
  // workspace layout (bytes)
  ushort* Kb      = (ushort*)(ws + 0);          //  8,388,608
  ushort* Qb      = (ushort*)(ws + 8388608);    //  8,388,608
  ushort* VT      = (ushort*)(ws + 16777216);   //  8,388,608
  float*  rcp_l   = (float*)(ws + 25165824);    //     32,768
  float*  rowpart = (float*)(ws + 25198592);    //  2,097,152
  ushort* Sb      = (ushort*)(ws + 27295744);   // 16,777,216 (dead after k_kvq)
  ushort* Wb      = (ushort*)(ws + 44072960);   //  3,145,728 (dead after k_kvq)
  // E (bf16, 134,217,728 B) overlays Sb/Wb (dead after k_kvq).
  const size_t E_WS_OFF = 27295744;
  // split-K partial slabs p1..p3 (16 MB fp32 each) past E; p0 = mbar region.
  const size_t P_WS_OFF = E_WS_OFF + 134217728;          // 161,513,472
  const size_t REQ = P_WS_OFF + 3 * 16777216;            // 211,845,120
  const bool ws_mode = (ws_size >= REQ);  // r9/r11 ran ws_mode -> ws >= 212MB
  ushort* E = ws_mode ? (ushort*)(ws + E_WS_OFF)
                      : (ushort*)((char*)attn + 134217728);

  k_convert<<<dim3(2048), dim3(256), 0, stream>>>(u, z, Wk, Wv, Wq, Sb, Wb);
  k_kvq<<<dim3(64, 12), dim3(256), 0, stream>>>(Sb, Wb, bk, bv, bq, Kb, Qb, VT);
  k_scores<<<dim3(4096), dim3(256), 0, stream>>>(Qb, Kb, E, rowpart);
  k_rcp<<<dim3(32), dim3(256), 0, stream>>>(rowpart, rcp_l);

  if (ws_mode) {
    float* part1 = (float*)(ws + P_WS_OFF);
    float* part2 = (float*)(ws + P_WS_OFF + 16777216);
    float* part3 = (float*)(ws + P_WS_OFF + 33554432);
    // 1024 PV blocks (split-K x4) with in-loop fused attn write.
    k_pv_norm<<<dim3(1024), dim3(256), 0, stream>>>(
        E, VT, rcp_l, mbar, part1, part2, part3, attn);
    k_reduce4<<<dim3(4096), dim3(256), 0, stream>>>(mbar, part1, part2, part3,
                                                    rcp_l);
  } else {
    // Fallback: E aliases attn upper half -> keep strict ordering.
    float* part1 = attn;  // lower 16MB, free until phased norm
    k_pv<<<dim3(4, 2, 64), dim3(256), 0, stream>>>(E, VT, mbar, part1);
    k_reduce2<<<dim3(4096), dim3(256), 0, stream>>>(mbar, part1, rcp_l);
    static const int ph[] = {0, 4096, 6144, 7168, 7680, 7936, 8064, 8128,
                             8160, 8176, 8184, 8188, 8190, 8191};
    for (int p = 0; p + 1 < (int)(sizeof(ph) / sizeof(ph[0])); ++p) {
      int a = ph[p], b = ph[p + 1];
      int units = (b - a) << 10;
      int blocks = (units + 255) / 256;
      if (blocks > 2048) blocks = 2048;
      k_norm<<<dim3(blocks), dim3(256), 0, stream>>>(E, attn, rcp_l, a, b - a);
    }
    k_lastrow<<<dim3(1), dim3(256), 0, stream>>>(E, attn, rcp_l);
  }
}

// Round 13
// 368.850 us; speedup vs baseline: 1.5867x; 1.5867x over previous
//
#include <hip/hip_runtime.h>
#include <hip/hip_bf16.h>
#include <stdint.h>

// Problem constants
#define N_TOK 8192
#define IN_DIM 1024
#define CDIM 512
#define NW 1536  // 3*CDIM stacked Wk,Wv,Wq

typedef short bf16x8 __attribute__((ext_vector_type(8)));
typedef float f32x4 __attribute__((ext_vector_type(4)));

__device__ __forceinline__ unsigned short f2bf(float f) {
  union { float f; unsigned int u; } x; x.f = f;
  unsigned int u = x.u;
  u += 0x7fffu + ((u >> 16) & 1u);   // round-to-nearest-even
  return (unsigned short)(u >> 16);
}
__device__ __forceinline__ float bf2f(unsigned short us) {
  union { unsigned int u; float f; } x; x.u = ((unsigned int)us) << 16;
  return x.f;
}

#define GLD16(g, l) __builtin_amdgcn_global_load_lds( \
    (const __attribute__((address_space(1))) void*)(g), \
    (__attribute__((address_space(3))) void*)(l), 16, 0, 0)

// ---------------------------------------------------------------------------
// K0: convert fp32 inputs -> bf16 staging buffers.
// ---------------------------------------------------------------------------
__global__ __launch_bounds__(256) void k_convert(
    const float* __restrict__ u, const float* __restrict__ z,
    const float* __restrict__ wk, const float* __restrict__ wv,
    const float* __restrict__ wq,
    ushort* __restrict__ Sb, ushort* __restrict__ Wb) {
  const int S4 = N_TOK * IN_DIM / 4;   // 2097152
  const int W4 = NW * IN_DIM / 4;      // 393216
  const int total = S4 + W4;
  for (int e = blockIdx.x * blockDim.x + threadIdx.x; e < total;
       e += gridDim.x * blockDim.x) {
    float4 v; ushort* dst;
    if (e < S4) {
      int idx = e << 2; int row = idx >> 10; int col = idx & 1023;
      const float* src = (col < 512) ? (u + row * 512 + col)
                                     : (z + row * 512 + (col - 512));
      v = *(const float4*)src;
      dst = Sb + idx;
    } else {
      int idx = (e - S4) << 2; int row = idx >> 10; int col = idx & 1023;
      const float* base = (row < 512) ? wk : (row < 1024 ? wv : wq);
      v = *(const float4*)(base + (size_t)(row & 511) * 1024 + col);
      dst = Wb + idx;
    }
    ushort4 o;
    o.x = f2bf(v.x); o.y = f2bf(v.y); o.z = f2bf(v.z); o.w = f2bf(v.w);
    *(ushort4*)dst = o;
  }
}

// ---------------------------------------------------------------------------
// K1: fused K/V/Q projection (bt-GEMM, 128x128 tile, BK=64).
// ---------------------------------------------------------------------------
__global__ __launch_bounds__(256) void k_kvq(
    const ushort* __restrict__ Sb, const ushort* __restrict__ Wb,
    const float* __restrict__ bk, const float* __restrict__ bv,
    const float* __restrict__ bq,
    ushort* __restrict__ Kb, ushort* __restrict__ Qb, ushort* __restrict__ VT) {
  __shared__ __align__(16) ushort As[128 * 64];
  __shared__ __align__(16) ushort Bs[128 * 64];
  const int tid = threadIdx.x, lane = tid & 63, w = tid >> 6;
  const int wr = w >> 1, wc = w & 1;
  const int tm = blockIdx.x, tn = blockIdx.y;

  f32x4 acc[4][4];
#pragma unroll
  for (int m = 0; m < 4; m++)
#pragma unroll
    for (int n = 0; n < 4; n++) acc[m][n] = (f32x4){0.f, 0.f, 0.f, 0.f};

  const ushort* ga0 = Sb + (size_t)tm * 128 * IN_DIM;
  const ushort* gb0 = Wb + (size_t)tn * 128 * IN_DIM;

  for (int k0 = 0; k0 < IN_DIM; k0 += 64) {
#pragma unroll
    for (int i = 0; i < 4; i++) {
      int ce = i * 256 + tid;
      int row = ce >> 3, c8 = (ce & 7) << 3;
      GLD16(ga0 + (size_t)row * IN_DIM + k0 + c8, As + ce * 8);
      GLD16(gb0 + (size_t)row * IN_DIM + k0 + c8, Bs + ce * 8);
    }
    __syncthreads();
#pragma unroll
    for (int kb = 0; kb < 2; kb++) {
      bf16x8 af[4], bfr[4];
#pragma unroll
      for (int m = 0; m < 4; m++)
        af[m] = *(const bf16x8*)(As + (wr * 64 + m * 16 + (lane & 15)) * 64 +
                                 kb * 32 + ((lane >> 4) << 3));
#pragma unroll
      for (int n = 0; n < 4; n++)
        bfr[n] = *(const bf16x8*)(Bs + (wc * 64 + n * 16 + (lane & 15)) * 64 +
                                  kb * 32 + ((lane >> 4) << 3));
#pragma unroll
      for (int m = 0; m < 4; m++)
#pragma unroll
        for (int n = 0; n < 4; n++)
          acc[m][n] = __builtin_amdgcn_mfma_f32_16x16x32_bf16(af[m], bfr[n],
                                                              acc[m][n], 0, 0, 0);
    }
    __syncthreads();
  }

  const int region = tn >> 2;                 // 0=K 1=V 2=Q
  const int colr = (tn & 3) * 128 + wc * 64;
  const int rbase = tm * 128 + wr * 64;
  const float* bias = (region == 0) ? bk : (region == 1 ? bv : bq);
  if (region == 1) {
#pragma unroll
    for (int m = 0; m < 4; m++) {
      int r0 = rbase + m * 16 + ((lane >> 4) << 2);
#pragma unroll
      for (int n = 0; n < 4; n++) {
        int c = colr + n * 16 + (lane & 15);
        float b = bias[c];
        ushort4 pk;
        pk.x = f2bf(acc[m][n][0] + b);
        pk.y = f2bf(acc[m][n][1] + b);
        pk.z = f2bf(acc[m][n][2] + b);
        pk.w = f2bf(acc[m][n][3] + b);
        *(ushort4*)(VT + (size_t)c * N_TOK + r0) = pk;  // transposed store
      }
    }
  } else {
    ushort* O = (region == 0) ? Kb : Qb;
#pragma unroll
    for (int m = 0; m < 4; m++) {
      int r0 = rbase + m * 16 + ((lane >> 4) << 2);
#pragma unroll
      for (int n = 0; n < 4; n++) {
        int c = colr + n * 16 + (lane & 15);
        float b = bias[c];
#pragma unroll
        for (int rg = 0; rg < 4; rg++)
          O[(size_t)(r0 + rg) * CDIM + c] = f2bf(acc[m][n][rg] + b);
      }
    }
  }
}

// ---------------------------------------------------------------------------
// K2: scores = Q @ K^T / sqrt(512); E = bf16(exp(score)) (diag->0) + row sums.
// ---------------------------------------------------------------------------
__global__ __launch_bounds__(256) void k_scores(
    const ushort* __restrict__ Qb, const ushort* __restrict__ Kb,
    ushort* __restrict__ E, float* __restrict__ rowpart) {
  __shared__ __align__(16) ushort As[128 * 64];
  __shared__ __align__(16) ushort Bs[128 * 64];
  __shared__ float sums[256];
  const int tid = threadIdx.x, lane = tid & 63, w = tid >> 6;
  const int wr = w >> 1, wc = w & 1;
  const int bid = blockIdx.x;
  const int swz = (bid & 7) * 512 + (bid >> 3);  // XCD-contiguous remap
  const int tm = swz & 63, tn = swz >> 6;

  f32x4 acc[4][4];
#pragma unroll
  for (int m = 0; m < 4; m++)
#pragma unroll
    for (int n = 0; n < 4; n++) acc[m][n] = (f32x4){0.f, 0.f, 0.f, 0.f};

  const ushort* ga0 = Qb + (size_t)tm * 128 * CDIM;
  const ushort* gb0 = Kb + (size_t)tn * 128 * CDIM;

  for (int k0 = 0; k0 < CDIM; k0 += 64) {
#pragma unroll
    for (int i = 0; i < 4; i++) {
      int ce = i * 256 + tid;
      int row = ce >> 3, c8 = (ce & 7) << 3;
      GLD16(ga0 + (size_t)row * CDIM + k0 + c8, As + ce * 8);
      GLD16(gb0 + (size_t)row * CDIM + k0 + c8, Bs + ce * 8);
    }
    __syncthreads();
#pragma unroll
    for (int kb = 0; kb < 2; kb++) {
      bf16x8 af[4], bfr[4];
#pragma unroll
      for (int m = 0; m < 4; m++)
        af[m] = *(const bf16x8*)(As + (wr * 64 + m * 16 + (lane & 15)) * 64 +
                                 kb * 32 + ((lane >> 4) << 3));
#pragma unroll
      for (int n = 0; n < 4; n++)
        bfr[n] = *(const bf16x8*)(Bs + (wc * 64 + n * 16 + (lane & 15)) * 64 +
                                  kb * 32 + ((lane >> 4) << 3));
#pragma unroll
      for (int m = 0; m < 4; m++)
#pragma unroll
        for (int n = 0; n < 4; n++)
          acc[m][n] = __builtin_amdgcn_mfma_f32_16x16x32_bf16(af[m], bfr[n],
                                                              acc[m][n], 0, 0, 0);
    }
    __syncthreads();
  }

  const float scale = 0.044194173824159216f;  // 1/sqrt(512)
  float rs[4][4];
#pragma unroll
  for (int m = 0; m < 4; m++)
#pragma unroll
    for (int rg = 0; rg < 4; rg++) rs[m][rg] = 0.f;

#pragma unroll
  for (int m = 0; m < 4; m++) {
    int grow_b = tm * 128 + wr * 64 + m * 16 + ((lane >> 4) << 2);
#pragma unroll
    for (int n = 0; n < 4; n++) {
      int gcol = tn * 128 + wc * 64 + n * 16 + (lane & 15);
#pragma unroll
      for (int rg = 0; rg < 4; rg++) {
        int grow = grow_b + rg;
        float ev = (grow == gcol) ? 0.0f : __expf(acc[m][n][rg] * scale);
        unsigned short evb = f2bf(ev);
        E[(size_t)grow * N_TOK + gcol] = evb;
        rs[m][rg] += bf2f(evb);
      }
    }
  }
#pragma unroll
  for (int m = 0; m < 4; m++)
#pragma unroll
    for (int rg = 0; rg < 4; rg++) {
      float s = rs[m][rg];
      s += __shfl_xor(s, 1);
      s += __shfl_xor(s, 2);
      s += __shfl_xor(s, 4);
      s += __shfl_xor(s, 8);
      rs[m][rg] = s;
    }
  if ((lane & 15) == 0) {
#pragma unroll
    for (int m = 0; m < 4; m++)
#pragma unroll
      for (int rg = 0; rg < 4; rg++)
        sums[wc * 128 + wr * 64 + m * 16 + ((lane >> 4) << 2) + rg] = rs[m][rg];
  }
  __syncthreads();
  if (tid < 128)
    rowpart[(size_t)(tm * 128 + tid) * 64 + tn] = sums[tid] + sums[128 + tid];
}

// ---------------------------------------------------------------------------
// K2c: rcp_l[row] = 1 / sum_j E[row][j]
// ---------------------------------------------------------------------------
__global__ __launch_bounds__(256) void k_rcp(const float* __restrict__ rowpart,
                                             float* __restrict__ rcp_l) {
  int row = blockIdx.x * blockDim.x + threadIdx.x;
  if (row < N_TOK) {
    const float4* p = (const float4*)(rowpart + (size_t)row * 64);
    float s = 0.f;
#pragma unroll
    for (int i = 0; i < 16; i++) {
      float4 v = p[i];
      s += v.x + v.y + v.z + v.w;
    }
    rcp_l[row] = 1.0f / s;
  }
}

// ---------------------------------------------------------------------------
// K3 (ws_mode): block-specialized FUSED kernel (round-8 proven layout).
//  - blocks [0,512): split-K(x2) PV, m97 structure; bid%8 == tm&7 keeps the
//    8 blocks sharing an E tm-panel on one XCD.
//  - blocks [512,2048): grid-stride attn normalize.
// ---------------------------------------------------------------------------
__global__ __launch_bounds__(256) void k_pv_fused(
    const ushort* __restrict__ E, const ushort* __restrict__ VT,
    const float* __restrict__ rcp_l, float* __restrict__ part0,
    float* __restrict__ part1, float* __restrict__ attn) {
  __shared__ __align__(16) ushort As[128 * 64];
  __shared__ __align__(16) ushort Bs[128 * 64];
  const int bid = blockIdx.x;
  const int tid = threadIdx.x;

  if (bid >= 512) {
    // ---------------- norm blocks: attn = float(E) * rcp_l ----------------
    const int units = N_TOK * 1024;  // 8-elem units
    const int stride = 1536 * 256;
    for (int uidx = (bid - 512) * 256 + tid; uidx < units; uidx += stride) {
      int row = uidx >> 10;
      int c8 = (uidx & 1023) << 3;
      const float rl = rcp_l[row];
      uint4 ev = *(const uint4*)(E + ((size_t)row << 13) + c8);
      float4 o0, o1;
      o0.x = bf2f((unsigned short)(ev.x & 0xffffu)) * rl;
      o0.y = bf2f((unsigned short)(ev.x >> 16)) * rl;
      o0.z = bf2f((unsigned short)(ev.y & 0xffffu)) * rl;
      o0.w = bf2f((unsigned short)(ev.y >> 16)) * rl;
      o1.x = bf2f((unsigned short)(ev.z & 0xffffu)) * rl;
      o1.y = bf2f((unsigned short)(ev.z >> 16)) * rl;
      o1.z = bf2f((unsigned short)(ev.w & 0xffffu)) * rl;
      o1.w = bf2f((unsigned short)(ev.w >> 16)) * rl;
      float* op = attn + ((size_t)row << 13) + c8;
      *(float4*)op = o0;
      *(float4*)(op + 4) = o1;
    }
    return;
  }

  // ------------------------------ PV blocks ------------------------------
  const int lane = tid & 63, w = tid >> 6;
  const int wr = w >> 1, wc = w & 1;
  const int inner = (bid >> 3) & 7;            // kz*4 + tn
  const int tn = inner & 3, kz = inner >> 2;
  const int tm = ((bid >> 6) << 3) | (bid & 7);
  const int kbase = kz << 12;  // kz*4096, 64 K-steps of 64

  f32x4 acc[4][4];
#pragma unroll
  for (int m = 0; m < 4; m++)
#pragma unroll
    for (int n = 0; n < 4; n++) acc[m][n] = (f32x4){0.f, 0.f, 0.f, 0.f};

  const ushort* ga0 = E + (size_t)tm * 128 * N_TOK;
  const ushort* gb0 = VT + (size_t)tn * 128 * N_TOK;
  const int sx = lane & 7;  // read-side swizzle (frag row&7 == lane&7)

  for (int k0 = kbase; k0 < kbase + 4096; k0 += 64) {
#pragma unroll
    for (int i = 0; i < 4; i++) {
      int ce = i * 256 + tid;
      int row = ce >> 3;
      int c8 = ((ce & 7) ^ (row & 7)) << 3;  // pre-swizzled source chunk
      GLD16(ga0 + (size_t)row * N_TOK + k0 + c8, As + ce * 8);
      GLD16(gb0 + (size_t)row * N_TOK + k0 + c8, Bs + ce * 8);
    }
    __syncthreads();
#pragma unroll
    for (int kb = 0; kb < 2; kb++) {
      const int chunk = ((kb * 4 + (lane >> 4)) ^ sx) << 3;
      bf16x8 af[4], bfr[4];
#pragma unroll
      for (int m = 0; m < 4; m++)
        af[m] = *(const bf16x8*)(As + (wr * 64 + m * 16 + (lane & 15)) * 64 +
                                 chunk);
#pragma unroll
      for (int n = 0; n < 4; n++)
        bfr[n] = *(const bf16x8*)(Bs + (wc * 64 + n * 16 + (lane & 15)) * 64 +
                                  chunk);
#pragma unroll
      for (int m = 0; m < 4; m++)
#pragma unroll
        for (int n = 0; n < 4; n++)
          acc[m][n] = __builtin_amdgcn_mfma_f32_16x16x32_bf16(af[m], bfr[n],
                                                              acc[m][n], 0, 0, 0);
    }
    __syncthreads();
  }

  float* P = kz ? part1 : part0;
#pragma unroll
  for (int m = 0; m < 4; m++) {
    int r0 = tm * 128 + wr * 64 + m * 16 + ((lane >> 4) << 2);
#pragma unroll
    for (int n = 0; n < 4; n++) {
      int c = tn * 128 + wc * 64 + n * 16 + (lane & 15);
#pragma unroll
      for (int rg = 0; rg < 4; rg++)
        P[(size_t)(r0 + rg) * CDIM + c] = acc[m][n][rg];
    }
  }
}

// ---------------------------------------------------------------------------
// K3-fb (fallback only): pure split-K(x2) PV, same structure, 3D grid.
// ---------------------------------------------------------------------------
__global__ __launch_bounds__(256) void k_pv(
    const ushort* __restrict__ E, const ushort* __restrict__ VT,
    float* __restrict__ part0, float* __restrict__ part1) {
  __shared__ __align__(16) ushort As[128 * 64];
  __shared__ __align__(16) ushort Bs[128 * 64];
  const int tid = threadIdx.x, lane = tid & 63, w = tid >> 6;
  const int wr = w >> 1, wc = w & 1;
  const int tn = blockIdx.x, kz = blockIdx.y, tm = blockIdx.z;
  const int kbase = kz << 12;

  f32x4 acc[4][4];
#pragma unroll
  for (int m = 0; m < 4; m++)
#pragma unroll
    for (int n = 0; n < 4; n++) acc[m][n] = (f32x4){0.f, 0.f, 0.f, 0.f};

  const ushort* ga0 = E + (size_t)tm * 128 * N_TOK;
  const ushort* gb0 = VT + (size_t)tn * 128 * N_TOK;
  const int sx = lane & 7;

  for (int k0 = kbase; k0 < kbase + 4096; k0 += 64) {
#pragma unroll
    for (int i = 0; i < 4; i++) {
      int ce = i * 256 + tid;
      int row = ce >> 3;
      int c8 = ((ce & 7) ^ (row & 7)) << 3;
      GLD16(ga0 + (size_t)row * N_TOK + k0 + c8, As + ce * 8);
      GLD16(gb0 + (size_t)row * N_TOK + k0 + c8, Bs + ce * 8);
    }
    __syncthreads();
#pragma unroll
    for (int kb = 0; kb < 2; kb++) {
      const int chunk = ((kb * 4 + (lane >> 4)) ^ sx) << 3;
      bf16x8 af[4], bfr[4];
#pragma unroll
      for (int m = 0; m < 4; m++)
        af[m] = *(const bf16x8*)(As + (wr * 64 + m * 16 + (lane & 15)) * 64 +
                                 chunk);
#pragma unroll
      for (int n = 0; n < 4; n++)
        bfr[n] = *(const bf16x8*)(Bs + (wc * 64 + n * 16 + (lane & 15)) * 64 +
                                  chunk);
#pragma unroll
      for (int m = 0; m < 4; m++)
#pragma unroll
        for (int n = 0; n < 4; n++)
          acc[m][n] = __builtin_amdgcn_mfma_f32_16x16x32_bf16(af[m], bfr[n],
                                                              acc[m][n], 0, 0, 0);
    }
    __syncthreads();
  }

  float* P = kz ? part1 : part0;
#pragma unroll
  for (int m = 0; m < 4; m++) {
    int r0 = tm * 128 + wr * 64 + m * 16 + ((lane >> 4) << 2);
#pragma unroll
    for (int n = 0; n < 4; n++) {
      int c = tn * 128 + wc * 64 + n * 16 + (lane & 15);
#pragma unroll
      for (int rg = 0; rg < 4; rg++)
        P[(size_t)(r0 + rg) * CDIM + c] = acc[m][n][rg];
    }
  }
}

// ---------------------------------------------------------------------------
// K3b: mbar = (p0+p1) * rcp_l  (p0 lives in the mbar region; in-place).
// ---------------------------------------------------------------------------
__global__ __launch_bounds__(256) void k_reduce2(
    float* __restrict__ p0, const float* __restrict__ p1,
    const float* __restrict__ rcp_l) {
  int idx4 = blockIdx.x * blockDim.x + threadIdx.x;
  const int T4 = N_TOK * CDIM / 4;
  if (idx4 < T4) {
    int row = idx4 >> 7;
    float rl = rcp_l[row];
    float4 a = ((const float4*)p0)[idx4];
    float4 b = ((const float4*)p1)[idx4];
    float4 o;
    o.x = (a.x + b.x) * rl; o.y = (a.y + b.y) * rl;
    o.z = (a.z + b.z) * rl; o.w = (a.w + b.w) * rl;
    ((float4*)p0)[idx4] = o;
  }
}

// ---------------------------------------------------------------------------
// K4 (fallback only): attn[row][j] = float(E[row][j]) * rcp_l[row]
// ---------------------------------------------------------------------------
__global__ __launch_bounds__(256) void k_norm(
    const ushort* __restrict__ E, float* __restrict__ attn,
    const float* __restrict__ rcp_l, int row0, int nrows) {
  const int units = nrows << 10;
  for (int uidx = blockIdx.x * blockDim.x + threadIdx.x; uidx < units;
       uidx += gridDim.x * blockDim.x) {
    int row = row0 + (uidx >> 10);
    int c8 = (uidx & 1023) << 3;
    const float rl = rcp_l[row];
    uint4 ev = *(const uint4*)(E + ((size_t)row << 13) + c8);
    float4 o0, o1;
    o0.x = bf2f((unsigned short)(ev.x & 0xffffu)) * rl;
    o0.y = bf2f((unsigned short)(ev.x >> 16)) * rl;
    o0.z = bf2f((unsigned short)(ev.y & 0xffffu)) * rl;
    o0.w = bf2f((unsigned short)(ev.y >> 16)) * rl;
    o1.x = bf2f((unsigned short)(ev.z & 0xffffu)) * rl;
    o1.y = bf2f((unsigned short)(ev.z >> 16)) * rl;
    o1.z = bf2f((unsigned short)(ev.w & 0xffffu)) * rl;
    o1.w = bf2f((unsigned short)(ev.w >> 16)) * rl;
    float* op = attn + ((size_t)row << 13) + c8;
    *(float4*)op = o0;
    *(float4*)(op + 4) = o1;
  }
}

// ---------------------------------------------------------------------------
// K4b (fallback only): last row — overlaps its own E source; regs first.
// ---------------------------------------------------------------------------
__global__ __launch_bounds__(256) void k_lastrow(
    const ushort* __restrict__ E, float* __restrict__ attn,
    const float* __restrict__ rcp_l) {
  const int row = N_TOK - 1;
  const int t = threadIdx.x;
  const float rl = rcp_l[row];
  const uint4* src = (const uint4*)(E + ((size_t)row << 13)) + t * 4;
  uint4 rr[4] = {src[0], src[1], src[2], src[3]};
  __syncthreads();
  float* dst = attn + ((size_t)row << 13) + t * 32;
#pragma unroll
  for (int q = 0; q < 4; q++) {
    float4 o0, o1;
    o0.x = bf2f((unsigned short)(rr[q].x & 0xffffu)) * rl;
    o0.y = bf2f((unsigned short)(rr[q].x >> 16)) * rl;
    o0.z = bf2f((unsigned short)(rr[q].y & 0xffffu)) * rl;
    o0.w = bf2f((unsigned short)(rr[q].y >> 16)) * rl;
    o1.x = bf2f((unsigned short)(rr[q].z & 0xffffu)) * rl;
    o1.y = bf2f((unsigned short)(rr[q].z >> 16)) * rl;
    o1.z = bf2f((unsigned short)(rr[q].w & 0xffffu)) * rl;
    o1.w = bf2f((unsigned short)(rr[q].w >> 16)) * rl;
    *(float4*)(dst + q * 8) = o0;
    *(float4*)(dst + q * 8 + 4) = o1;
  }
}

// ---------------------------------------------------------------------------
extern "C" void kernel_launch(void* const* d_in, const int* in_sizes, int n_in,
                              void* d_out, int out_size, void* d_ws,
                              size_t ws_size, hipStream_t stream) {
  const float* u  = (const float*)d_in[0];
  const float* z  = (const float*)d_in[1];
  const float* Wk = (const float*)d_in[2];
  const float* bk = (const float*)d_in[3];
  const float* Wv = (const float*)d_in[4];
  const float* bv = (const float*)d_in[5];
  const float* Wq = (const float*)d_in[6];
  const float* bq = (const float*)d_in[7];

  float* mbar = (float*)d_out;
  float* attn = (float*)d_out + (size_t)N_TOK * CDIM;

  char* ws = (char*)d_ws;
  // workspace layout (bytes)
  ushort* Kb      = (ushort*)(ws + 0);          //  8,388,608
  ushort* Qb      = (ushort*)(ws + 8388608);    //  8,388,608
  ushort* VT      = (ushort*)(ws + 16777216);   //  8,388,608
  float*  rcp_l   = (float*)(ws + 25165824);    //     32,768
  float*  rowpart = (float*)(ws + 25198592);    //  2,097,152
  ushort* Sb      = (ushort*)(ws + 27295744);   // 16,777,216 (dead after k_kvq)
  ushort* Wb      = (ushort*)(ws + 44072960);   //  3,145,728 (dead after k_kvq)
  // part1 (16MB fp32) overlays Kb+Qb (dead after k_scores).
  float*  part1ws = (float*)(ws + 0);
  // E (bf16, 134,217,728 B): workspace if it fits, else attn upper half.
  const size_t E_WS_OFF = 27295744;
  const size_t REQ = E_WS_OFF + 134217728;  // 161,513,472
  const bool ws_mode = (ws_size >= REQ);
  ushort* E = ws_mode ? (ushort*)(ws + E_WS_OFF)
                      : (ushort*)((char*)attn + 134217728);

  k_convert<<<dim3(2048), dim3(256), 0, stream>>>(u, z, Wk, Wv, Wq, Sb, Wb);
  k_kvq<<<dim3(64, 12), dim3(256), 0, stream>>>(Sb, Wb, bk, bv, bq, Kb, Qb, VT);
  k_scores<<<dim3(4096), dim3(256), 0, stream>>>(Qb, Kb, E, rowpart);
  k_rcp<<<dim3(32), dim3(256), 0, stream>>>(rowpart, rcp_l);

  if (ws_mode) {
    // PV (512 blocks) + attn-normalize (1536 blocks) fused (round-8 layout).
    k_pv_fused<<<dim3(2048), dim3(256), 0, stream>>>(E, VT, rcp_l, mbar,
                                                     part1ws, attn);
    k_reduce2<<<dim3(4096), dim3(256), 0, stream>>>(mbar, part1ws, rcp_l);
  } else {
    // Fallback: E aliases attn upper half -> keep strict ordering.
    float* part1 = attn;  // lower 16MB, free until phased norm
    k_pv<<<dim3(4, 2, 64), dim3(256), 0, stream>>>(E, VT, mbar, part1);
    k_reduce2<<<dim3(4096), dim3(256), 0, stream>>>(mbar, part1, rcp_l);
    static const int ph[] = {0, 4096, 6144, 7168, 7680, 7936, 8064, 8128,
                             8160, 8176, 8184, 8188, 8190, 8191};
    for (int p = 0; p + 1 < (int)(sizeof(ph) / sizeof(ph[0])); ++p) {
      int a = ph[p], b = ph[p + 1];
      int units = (b - a) << 10;
      int blocks = (units + 255) / 256;
      if (blocks > 2048) blocks = 2048;
      k_norm<<<dim3(blocks), dim3(256), 0, stream>>>(E, attn, rcp_l, a, b - a);
    }
    k_lastrow<<<dim3(1), dim3(256), 0, stream>>>(E, attn, rcp_l);
  }
}

// Round 14
// 361.235 us; speedup vs baseline: 1.6202x; 1.0211x over previous
//
#include <hip/hip_runtime.h>
#include <hip/hip_bf16.h>
#include <stdint.h>

// Problem constants
#define N_TOK 8192
#define IN_DIM 1024
#define CDIM 512
#define NW 1536  // 3*CDIM stacked Wk,Wv,Wq

typedef short bf16x8 __attribute__((ext_vector_type(8)));
typedef float f32x4 __attribute__((ext_vector_type(4)));

__device__ __forceinline__ unsigned short f2bf(float f) {
  union { float f; unsigned int u; } x; x.f = f;
  unsigned int u = x.u;
  u += 0x7fffu + ((u >> 16) & 1u);   // round-to-nearest-even
  return (unsigned short)(u >> 16);
}
__device__ __forceinline__ float bf2f(unsigned short us) {
  union { unsigned int u; float f; } x; x.u = ((unsigned int)us) << 16;
  return x.f;
}

#define GLD16(g, l) __builtin_amdgcn_global_load_lds( \
    (const __attribute__((address_space(1))) void*)(g), \
    (__attribute__((address_space(3))) void*)(l), 16, 0, 0)

// ---------------------------------------------------------------------------
// K0: convert fp32 inputs -> bf16 staging buffers.
// ---------------------------------------------------------------------------
__global__ __launch_bounds__(256) void k_convert(
    const float* __restrict__ u, const float* __restrict__ z,
    const float* __restrict__ wk, const float* __restrict__ wv,
    const float* __restrict__ wq,
    ushort* __restrict__ Sb, ushort* __restrict__ Wb) {
  const int S4 = N_TOK * IN_DIM / 4;   // 2097152
  const int W4 = NW * IN_DIM / 4;      // 393216
  const int total = S4 + W4;
  for (int e = blockIdx.x * blockDim.x + threadIdx.x; e < total;
       e += gridDim.x * blockDim.x) {
    float4 v; ushort* dst;
    if (e < S4) {
      int idx = e << 2; int row = idx >> 10; int col = idx & 1023;
      const float* src = (col < 512) ? (u + row * 512 + col)
                                     : (z + row * 512 + (col - 512));
      v = *(const float4*)src;
      dst = Sb + idx;
    } else {
      int idx = (e - S4) << 2; int row = idx >> 10; int col = idx & 1023;
      const float* base = (row < 512) ? wk : (row < 1024 ? wv : wq);
      v = *(const float4*)(base + (size_t)(row & 511) * 1024 + col);
      dst = Wb + idx;
    }
    ushort4 o;
    o.x = f2bf(v.x); o.y = f2bf(v.y); o.z = f2bf(v.z); o.w = f2bf(v.w);
    *(ushort4*)dst = o;
  }
}

// ---------------------------------------------------------------------------
// K1: fused K/V/Q projection (bt-GEMM, 128x128 tile, BK=64).
// 1D grid (768) with XCD tm-slab swizzle: concurrent blocks per XCD cover
// tm-slab(8) x tn(12) -> working set ~2MB Sb + 3MB Wb ~ L2-fits (the old
// (64,12) grid walked all 16MB of Sb concurrently per XCD).
// ---------------------------------------------------------------------------
__global__ __launch_bounds__(256) void k_kvq(
    const ushort* __restrict__ Sb, const ushort* __restrict__ Wb,
    const float* __restrict__ bk, const float* __restrict__ bv,
    const float* __restrict__ bq,
    ushort* __restrict__ Kb, ushort* __restrict__ Qb, ushort* __restrict__ VT) {
  __shared__ __align__(16) ushort As[128 * 64];
  __shared__ __align__(16) ushort Bs[128 * 64];
  const int tid = threadIdx.x, lane = tid & 63, w = tid >> 6;
  const int wr = w >> 1, wc = w & 1;
  const int bid = blockIdx.x;
  const int tm = (bid & 7) * 8 + ((bid >> 3) & 7);  // XCD tm-slab
  const int tn = bid >> 6;                          // 0..11

  f32x4 acc[4][4];
#pragma unroll
  for (int m = 0; m < 4; m++)
#pragma unroll
    for (int n = 0; n < 4; n++) acc[m][n] = (f32x4){0.f, 0.f, 0.f, 0.f};

  const ushort* ga0 = Sb + (size_t)tm * 128 * IN_DIM;
  const ushort* gb0 = Wb + (size_t)tn * 128 * IN_DIM;

  for (int k0 = 0; k0 < IN_DIM; k0 += 64) {
#pragma unroll
    for (int i = 0; i < 4; i++) {
      int ce = i * 256 + tid;
      int row = ce >> 3, c8 = (ce & 7) << 3;
      GLD16(ga0 + (size_t)row * IN_DIM + k0 + c8, As + ce * 8);
      GLD16(gb0 + (size_t)row * IN_DIM + k0 + c8, Bs + ce * 8);
    }
    __syncthreads();
#pragma unroll
    for (int kb = 0; kb < 2; kb++) {
      bf16x8 af[4], bfr[4];
#pragma unroll
      for (int m = 0; m < 4; m++)
        af[m] = *(const bf16x8*)(As + (wr * 64 + m * 16 + (lane & 15)) * 64 +
                                 kb * 32 + ((lane >> 4) << 3));
#pragma unroll
      for (int n = 0; n < 4; n++)
        bfr[n] = *(const bf16x8*)(Bs + (wc * 64 + n * 16 + (lane & 15)) * 64 +
                                  kb * 32 + ((lane >> 4) << 3));
#pragma unroll
      for (int m = 0; m < 4; m++)
#pragma unroll
        for (int n = 0; n < 4; n++)
          acc[m][n] = __builtin_amdgcn_mfma_f32_16x16x32_bf16(af[m], bfr[n],
                                                              acc[m][n], 0, 0, 0);
    }
    __syncthreads();
  }

  const int region = tn >> 2;                 // 0=K 1=V 2=Q
  const int colr = (tn & 3) * 128 + wc * 64;
  const int rbase = tm * 128 + wr * 64;
  const float* bias = (region == 0) ? bk : (region == 1 ? bv : bq);
  if (region == 1) {
#pragma unroll
    for (int m = 0; m < 4; m++) {
      int r0 = rbase + m * 16 + ((lane >> 4) << 2);
#pragma unroll
      for (int n = 0; n < 4; n++) {
        int c = colr + n * 16 + (lane & 15);
        float b = bias[c];
        ushort4 pk;
        pk.x = f2bf(acc[m][n][0] + b);
        pk.y = f2bf(acc[m][n][1] + b);
        pk.z = f2bf(acc[m][n][2] + b);
        pk.w = f2bf(acc[m][n][3] + b);
        *(ushort4*)(VT + (size_t)c * N_TOK + r0) = pk;  // transposed store
      }
    }
  } else {
    ushort* O = (region == 0) ? Kb : Qb;
#pragma unroll
    for (int m = 0; m < 4; m++) {
      int r0 = rbase + m * 16 + ((lane >> 4) << 2);
#pragma unroll
      for (int n = 0; n < 4; n++) {
        int c = colr + n * 16 + (lane & 15);
        float b = bias[c];
#pragma unroll
        for (int rg = 0; rg < 4; rg++)
          O[(size_t)(r0 + rg) * CDIM + c] = f2bf(acc[m][n][rg] + b);
      }
    }
  }
}

// ---------------------------------------------------------------------------
// K2: scores = Q @ K^T / sqrt(512); E = bf16(exp(score)) (diag->0) + row sums.
// XCD tn-slab swizzle: each XCD owns tn in [xcd*8, xcd*8+8) with tm slow —
// concurrent working set 16 Q-panels (2MB) + 8 K-panels (1MB) fits the 4MB
// per-XCD L2. (Old swizzle walked the full 8MB Q per XCD: FETCH 266MB.)
// ---------------------------------------------------------------------------
__global__ __launch_bounds__(256) void k_scores(
    const ushort* __restrict__ Qb, const ushort* __restrict__ Kb,
    ushort* __restrict__ E, float* __restrict__ rowpart) {
  __shared__ __align__(16) ushort As[128 * 64];
  __shared__ __align__(16) ushort Bs[128 * 64];
  __shared__ float sums[256];
  const int tid = threadIdx.x, lane = tid & 63, w = tid >> 6;
  const int wr = w >> 1, wc = w & 1;
  const int bid = blockIdx.x;
  const int tm = bid >> 6;                            // 0..63 (slow)
  const int tn = (bid & 7) * 8 + ((bid >> 3) & 7);    // XCD tn-slab

  f32x4 acc[4][4];
#pragma unroll
  for (int m = 0; m < 4; m++)
#pragma unroll
    for (int n = 0; n < 4; n++) acc[m][n] = (f32x4){0.f, 0.f, 0.f, 0.f};

  const ushort* ga0 = Qb + (size_t)tm * 128 * CDIM;
  const ushort* gb0 = Kb + (size_t)tn * 128 * CDIM;

  for (int k0 = 0; k0 < CDIM; k0 += 64) {
#pragma unroll
    for (int i = 0; i < 4; i++) {
      int ce = i * 256 + tid;
      int row = ce >> 3, c8 = (ce & 7) << 3;
      GLD16(ga0 + (size_t)row * CDIM + k0 + c8, As + ce * 8);
      GLD16(gb0 + (size_t)row * CDIM + k0 + c8, Bs + ce * 8);
    }
    __syncthreads();
#pragma unroll
    for (int kb = 0; kb < 2; kb++) {
      bf16x8 af[4], bfr[4];
#pragma unroll
      for (int m = 0; m < 4; m++)
        af[m] = *(const bf16x8*)(As + (wr * 64 + m * 16 + (lane & 15)) * 64 +
                                 kb * 32 + ((lane >> 4) << 3));
#pragma unroll
      for (int n = 0; n < 4; n++)
        bfr[n] = *(const bf16x8*)(Bs + (wc * 64 + n * 16 + (lane & 15)) * 64 +
                                  kb * 32 + ((lane >> 4) << 3));
#pragma unroll
      for (int m = 0; m < 4; m++)
#pragma unroll
        for (int n = 0; n < 4; n++)
          acc[m][n] = __builtin_amdgcn_mfma_f32_16x16x32_bf16(af[m], bfr[n],
                                                              acc[m][n], 0, 0, 0);
    }
    __syncthreads();
  }

  const float scale = 0.044194173824159216f;  // 1/sqrt(512)
  float rs[4][4];
#pragma unroll
  for (int m = 0; m < 4; m++)
#pragma unroll
    for (int rg = 0; rg < 4; rg++) rs[m][rg] = 0.f;

#pragma unroll
  for (int m = 0; m < 4; m++) {
    int grow_b = tm * 128 + wr * 64 + m * 16 + ((lane >> 4) << 2);
#pragma unroll
    for (int n = 0; n < 4; n++) {
      int gcol = tn * 128 + wc * 64 + n * 16 + (lane & 15);
#pragma unroll
      for (int rg = 0; rg < 4; rg++) {
        int grow = grow_b + rg;
        float ev = (grow == gcol) ? 0.0f : __expf(acc[m][n][rg] * scale);
        unsigned short evb = f2bf(ev);
        E[(size_t)grow * N_TOK + gcol] = evb;
        rs[m][rg] += bf2f(evb);
      }
    }
  }
#pragma unroll
  for (int m = 0; m < 4; m++)
#pragma unroll
    for (int rg = 0; rg < 4; rg++) {
      float s = rs[m][rg];
      s += __shfl_xor(s, 1);
      s += __shfl_xor(s, 2);
      s += __shfl_xor(s, 4);
      s += __shfl_xor(s, 8);
      rs[m][rg] = s;
    }
  if ((lane & 15) == 0) {
#pragma unroll
    for (int m = 0; m < 4; m++)
#pragma unroll
      for (int rg = 0; rg < 4; rg++)
        sums[wc * 128 + wr * 64 + m * 16 + ((lane >> 4) << 2) + rg] = rs[m][rg];
  }
  __syncthreads();
  if (tid < 128)
    rowpart[(size_t)(tm * 128 + tid) * 64 + tn] = sums[tid] + sums[128 + tid];
}

// ---------------------------------------------------------------------------
// K2c: rcp_l[row] = 1 / sum_j E[row][j]
// ---------------------------------------------------------------------------
__global__ __launch_bounds__(256) void k_rcp(const float* __restrict__ rowpart,
                                             float* __restrict__ rcp_l) {
  int row = blockIdx.x * blockDim.x + threadIdx.x;
  if (row < N_TOK) {
    const float4* p = (const float4*)(rowpart + (size_t)row * 64);
    float s = 0.f;
#pragma unroll
    for (int i = 0; i < 16; i++) {
      float4 v = p[i];
      s += v.x + v.y + v.z + v.w;
    }
    rcp_l[row] = 1.0f / s;
  }
}

// ---------------------------------------------------------------------------
// K3 (ws_mode): block-specialized FUSED kernel (round-8 proven layout).
//  - blocks [0,512): split-K(x2) PV, m97 structure; bid%8 == tm&7 keeps the
//    8 blocks sharing an E tm-panel on one XCD.
//  - blocks [512,2048): grid-stride attn normalize.
// ---------------------------------------------------------------------------
__global__ __launch_bounds__(256) void k_pv_fused(
    const ushort* __restrict__ E, const ushort* __restrict__ VT,
    const float* __restrict__ rcp_l, float* __restrict__ part0,
    float* __restrict__ part1, float* __restrict__ attn) {
  __shared__ __align__(16) ushort As[128 * 64];
  __shared__ __align__(16) ushort Bs[128 * 64];
  const int bid = blockIdx.x;
  const int tid = threadIdx.x;

  if (bid >= 512) {
    // ---------------- norm blocks: attn = float(E) * rcp_l ----------------
    const int units = N_TOK * 1024;  // 8-elem units
    const int stride = 1536 * 256;
    for (int uidx = (bid - 512) * 256 + tid; uidx < units; uidx += stride) {
      int row = uidx >> 10;
      int c8 = (uidx & 1023) << 3;
      const float rl = rcp_l[row];
      uint4 ev = *(const uint4*)(E + ((size_t)row << 13) + c8);
      float4 o0, o1;
      o0.x = bf2f((unsigned short)(ev.x & 0xffffu)) * rl;
      o0.y = bf2f((unsigned short)(ev.x >> 16)) * rl;
      o0.z = bf2f((unsigned short)(ev.y & 0xffffu)) * rl;
      o0.w = bf2f((unsigned short)(ev.y >> 16)) * rl;
      o1.x = bf2f((unsigned short)(ev.z & 0xffffu)) * rl;
      o1.y = bf2f((unsigned short)(ev.z >> 16)) * rl;
      o1.z = bf2f((unsigned short)(ev.w & 0xffffu)) * rl;
      o1.w = bf2f((unsigned short)(ev.w >> 16)) * rl;
      float* op = attn + ((size_t)row << 13) + c8;
      *(float4*)op = o0;
      *(float4*)(op + 4) = o1;
    }
    return;
  }

  // ------------------------------ PV blocks ------------------------------
  const int lane = tid & 63, w = tid >> 6;
  const int wr = w >> 1, wc = w & 1;
  const int inner = (bid >> 3) & 7;            // kz*4 + tn
  const int tn = inner & 3, kz = inner >> 2;
  const int tm = ((bid >> 6) << 3) | (bid & 7);
  const int kbase = kz << 12;  // kz*4096, 64 K-steps of 64

  f32x4 acc[4][4];
#pragma unroll
  for (int m = 0; m < 4; m++)
#pragma unroll
    for (int n = 0; n < 4; n++) acc[m][n] = (f32x4){0.f, 0.f, 0.f, 0.f};

  const ushort* ga0 = E + (size_t)tm * 128 * N_TOK;
  const ushort* gb0 = VT + (size_t)tn * 128 * N_TOK;
  const int sx = lane & 7;  // read-side swizzle (frag row&7 == lane&7)

  for (int k0 = kbase; k0 < kbase + 4096; k0 += 64) {
#pragma unroll
    for (int i = 0; i < 4; i++) {
      int ce = i * 256 + tid;
      int row = ce >> 3;
      int c8 = ((ce & 7) ^ (row & 7)) << 3;  // pre-swizzled source chunk
      GLD16(ga0 + (size_t)row * N_TOK + k0 + c8, As + ce * 8);
      GLD16(gb0 + (size_t)row * N_TOK + k0 + c8, Bs + ce * 8);
    }
    __syncthreads();
#pragma unroll
    for (int kb = 0; kb < 2; kb++) {
      const int chunk = ((kb * 4 + (lane >> 4)) ^ sx) << 3;
      bf16x8 af[4], bfr[4];
#pragma unroll
      for (int m = 0; m < 4; m++)
        af[m] = *(const bf16x8*)(As + (wr * 64 + m * 16 + (lane & 15)) * 64 +
                                 chunk);
#pragma unroll
      for (int n = 0; n < 4; n++)
        bfr[n] = *(const bf16x8*)(Bs + (wc * 64 + n * 16 + (lane & 15)) * 64 +
                                  chunk);
#pragma unroll
      for (int m = 0; m < 4; m++)
#pragma unroll
        for (int n = 0; n < 4; n++)
          acc[m][n] = __builtin_amdgcn_mfma_f32_16x16x32_bf16(af[m], bfr[n],
                                                              acc[m][n], 0, 0, 0);
    }
    __syncthreads();
  }

  float* P = kz ? part1 : part0;
#pragma unroll
  for (int m = 0; m < 4; m++) {
    int r0 = tm * 128 + wr * 64 + m * 16 + ((lane >> 4) << 2);
#pragma unroll
    for (int n = 0; n < 4; n++) {
      int c = tn * 128 + wc * 64 + n * 16 + (lane & 15);
#pragma unroll
      for (int rg = 0; rg < 4; rg++)
        P[(size_t)(r0 + rg) * CDIM + c] = acc[m][n][rg];
    }
  }
}

// ---------------------------------------------------------------------------
// K3-fb (fallback only): pure split-K(x2) PV, same structure, 3D grid.
// ---------------------------------------------------------------------------
__global__ __launch_bounds__(256) void k_pv(
    const ushort* __restrict__ E, const ushort* __restrict__ VT,
    float* __restrict__ part0, float* __restrict__ part1) {
  __shared__ __align__(16) ushort As[128 * 64];
  __shared__ __align__(16) ushort Bs[128 * 64];
  const int tid = threadIdx.x, lane = tid & 63, w = tid >> 6;
  const int wr = w >> 1, wc = w & 1;
  const int tn = blockIdx.x, kz = blockIdx.y, tm = blockIdx.z;
  const int kbase = kz << 12;

  f32x4 acc[4][4];
#pragma unroll
  for (int m = 0; m < 4; m++)
#pragma unroll
    for (int n = 0; n < 4; n++) acc[m][n] = (f32x4){0.f, 0.f, 0.f, 0.f};

  const ushort* ga0 = E + (size_t)tm * 128 * N_TOK;
  const ushort* gb0 = VT + (size_t)tn * 128 * N_TOK;
  const int sx = lane & 7;

  for (int k0 = kbase; k0 < kbase + 4096; k0 += 64) {
#pragma unroll
    for (int i = 0; i < 4; i++) {
      int ce = i * 256 + tid;
      int row = ce >> 3;
      int c8 = ((ce & 7) ^ (row & 7)) << 3;
      GLD16(ga0 + (size_t)row * N_TOK + k0 + c8, As + ce * 8);
      GLD16(gb0 + (size_t)row * N_TOK + k0 + c8, Bs + ce * 8);
    }
    __syncthreads();
#pragma unroll
    for (int kb = 0; kb < 2; kb++) {
      const int chunk = ((kb * 4 + (lane >> 4)) ^ sx) << 3;
      bf16x8 af[4], bfr[4];
#pragma unroll
      for (int m = 0; m < 4; m++)
        af[m] = *(const bf16x8*)(As + (wr * 64 + m * 16 + (lane & 15)) * 64 +
                                 chunk);
#pragma unroll
      for (int n = 0; n < 4; n++)
        bfr[n] = *(const bf16x8*)(Bs + (wc * 64 + n * 16 + (lane & 15)) * 64 +
                                  chunk);
#pragma unroll
      for (int m = 0; m < 4; m++)
#pragma unroll
        for (int n = 0; n < 4; n++)
          acc[m][n] = __builtin_amdgcn_mfma_f32_16x16x32_bf16(af[m], bfr[n],
                                                              acc[m][n], 0, 0, 0);
    }
    __syncthreads();
  }

  float* P = kz ? part1 : part0;
#pragma unroll
  for (int m = 0; m < 4; m++) {
    int r0 = tm * 128 + wr * 64 + m * 16 + ((lane >> 4) << 2);
#pragma unroll
    for (int n = 0; n < 4; n++) {
      int c = tn * 128 + wc * 64 + n * 16 + (lane & 15);
#pragma unroll
      for (int rg = 0; rg < 4; rg++)
        P[(size_t)(r0 + rg) * CDIM + c] = acc[m][n][rg];
    }
  }
}

// ---------------------------------------------------------------------------
// K3b: mbar = (p0+p1) * rcp_l  (p0 lives in the mbar region; in-place).
// ---------------------------------------------------------------------------
__global__ __launch_bounds__(256) void k_reduce2(
    float* __restrict__ p0, const float* __restrict__ p1,
    const float* __restrict__ rcp_l) {
  int idx4 = blockIdx.x * blockDim.x + threadIdx.x;
  const int T4 = N_TOK * CDIM / 4;
  if (idx4 < T4) {
    int row = idx4 >> 7;
    float rl = rcp_l[row];
    float4 a = ((const float4*)p0)[idx4];
    float4 b = ((const float4*)p1)[idx4];
    float4 o;
    o.x = (a.x + b.x) * rl; o.y = (a.y + b.y) * rl;
    o.z = (a.z + b.z) * rl; o.w = (a.w + b.w) * rl;
    ((float4*)p0)[idx4] = o;
  }
}

// ---------------------------------------------------------------------------
// K4 (fallback only): attn[row][j] = float(E[row][j]) * rcp_l[row]
// ---------------------------------------------------------------------------
__global__ __launch_bounds__(256) void k_norm(
    const ushort* __restrict__ E, float* __restrict__ attn,
    const float* __restrict__ rcp_l, int row0, int nrows) {
  const int units = nrows << 10;
  for (int uidx = blockIdx.x * blockDim.x + threadIdx.x; uidx < units;
       uidx += gridDim.x * blockDim.x) {
    int row = row0 + (uidx >> 10);
    int c8 = (uidx & 1023) << 3;
    const float rl = rcp_l[row];
    uint4 ev = *(const uint4*)(E + ((size_t)row << 13) + c8);
    float4 o0, o1;
    o0.x = bf2f((unsigned short)(ev.x & 0xffffu)) * rl;
    o0.y = bf2f((unsigned short)(ev.x >> 16)) * rl;
    o0.z = bf2f((unsigned short)(ev.y & 0xffffu)) * rl;
    o0.w = bf2f((unsigned short)(ev.y >> 16)) * rl;
    o1.x = bf2f((unsigned short)(ev.z & 0xffffu)) * rl;
    o1.y = bf2f((unsigned short)(ev.z >> 16)) * rl;
    o1.z = bf2f((unsigned short)(ev.w & 0xffffu)) * rl;
    o1.w = bf2f((unsigned short)(ev.w >> 16)) * rl;
    float* op = attn + ((size_t)row << 13) + c8;
    *(float4*)op = o0;
    *(float4*)(op + 4) = o1;
  }
}

// ---------------------------------------------------------------------------
// K4b (fallback only): last row — overlaps its own E source; regs first.
// ---------------------------------------------------------------------------
__global__ __launch_bounds__(256) void k_lastrow(
    const ushort* __restrict__ E, float* __restrict__ attn,
    const float* __restrict__ rcp_l) {
  const int row = N_TOK - 1;
  const int t = threadIdx.x;
  const float rl = rcp_l[row];
  const uint4* src = (const uint4*)(E + ((size_t)row << 13)) + t * 4;
  uint4 rr[4] = {src[0], src[1], src[2], src[3]};
  __syncthreads();
  float* dst = attn + ((size_t)row << 13) + t * 32;
#pragma unroll
  for (int q = 0; q < 4; q++) {
    float4 o0, o1;
    o0.x = bf2f((unsigned short)(rr[q].x & 0xffffu)) * rl;
    o0.y = bf2f((unsigned short)(rr[q].x >> 16)) * rl;
    o0.z = bf2f((unsigned short)(rr[q].y & 0xffffu)) * rl;
    o0.w = bf2f((unsigned short)(rr[q].y >> 16)) * rl;
    o1.x = bf2f((unsigned short)(rr[q].z & 0xffffu)) * rl;
    o1.y = bf2f((unsigned short)(rr[q].z >> 16)) * rl;
    o1.z = bf2f((unsigned short)(rr[q].w & 0xffffu)) * rl;
    o1.w = bf2f((unsigned short)(rr[q].w >> 16)) * rl;
    *(float4*)(dst + q * 8) = o0;
    *(float4*)(dst + q * 8 + 4) = o1;
  }
}

// ---------------------------------------------------------------------------
extern "C" void kernel_launch(void* const* d_in, const int* in_sizes, int n_in,
                              void* d_out, int out_size, void* d_ws,
                              size_t ws_size, hipStream_t stream) {
  const float* u  = (const float*)d_in[0];
  const float* z  = (const float*)d_in[1];
  const float* Wk = (const float*)d_in[2];
  const float* bk = (const float*)d_in[3];
  const float* Wv = (const float*)d_in[4];
  const float* bv = (const float*)d_in[5];
  const float* Wq = (const float*)d_in[6];
  const float* bq = (const float*)d_in[7];

  float* mbar = (float*)d_out;
  float* attn = (float*)d_out + (size_t)N_TOK * CDIM;

  char* ws = (char*)d_ws;
  // workspace layout (bytes)
  ushort* Kb      = (ushort*)(ws + 0);          //  8,388,608
  ushort* Qb      = (ushort*)(ws + 8388608);    //  8,388,608
  ushort* VT      = (ushort*)(ws + 16777216);   //  8,388,608
  float*  rcp_l   = (float*)(ws + 25165824);    //     32,768
  float*  rowpart = (float*)(ws + 25198592);    //  2,097,152
  ushort* Sb      = (ushort*)(ws + 27295744);   // 16,777,216 (dead after k_kvq)
  ushort* Wb      = (ushort*)(ws + 44072960);   //  3,145,728 (dead after k_kvq)
  // part1 (16MB fp32) overlays Kb+Qb (dead after k_scores).
  float*  part1ws = (float*)(ws + 0);
  // E (bf16, 134,217,728 B): workspace if it fits, else attn upper half.
  const size_t E_WS_OFF = 27295744;
  const size_t REQ = E_WS_OFF + 134217728;  // 161,513,472
  const bool ws_mode = (ws_size >= REQ);
  ushort* E = ws_mode ? (ushort*)(ws + E_WS_OFF)
                      : (ushort*)((char*)attn + 134217728);

  k_convert<<<dim3(2048), dim3(256), 0, stream>>>(u, z, Wk, Wv, Wq, Sb, Wb);
  k_kvq<<<dim3(768), dim3(256), 0, stream>>>(Sb, Wb, bk, bv, bq, Kb, Qb, VT);
  k_scores<<<dim3(4096), dim3(256), 0, stream>>>(Qb, Kb, E, rowpart);
  k_rcp<<<dim3(32), dim3(256), 0, stream>>>(rowpart, rcp_l);

  if (ws_mode) {
    // PV (512 blocks) + attn-normalize (1536 blocks) fused (round-8 layout).
    k_pv_fused<<<dim3(2048), dim3(256), 0, stream>>>(E, VT, rcp_l, mbar,
                                                     part1ws, attn);
    k_reduce2<<<dim3(4096), dim3(256), 0, stream>>>(mbar, part1ws, rcp_l);
  } else {
    // Fallback: E aliases attn upper half -> keep strict ordering.
    float* part1 = attn;  // lower 16MB, free until phased norm
    k_pv<<<dim3(4, 2, 64), dim3(256), 0, stream>>>(E, VT, mbar, part1);
    k_reduce2<<<dim3(4096), dim3(256), 0, stream>>>(mbar, part1, rcp_l);
    static const int ph[] = {0, 4096, 6144, 7168, 7680, 7936, 8064, 8128,
                             8160, 8176, 8184, 8188, 8190, 8191};
    for (int p = 0; p + 1 < (int)(sizeof(ph) / sizeof(ph[0])); ++p) {
      int a = ph[p], b = ph[p + 1];
      int units = (b - a) << 10;
      int blocks = (units + 255) / 256;
      if (blocks > 2048) blocks = 2048;
      k_norm<<<dim3(blocks), dim3(256), 0, stream>>>(E, attn, rcp_l, a, b - a);
    }
    k_lastrow<<<dim3(1), dim3(256), 0, stream>>>(E, attn, rcp_l);
  }
}